// Round 8
// baseline (5190.028 us; speedup 1.0000x reference)
//
#include <hip/hip_runtime.h>

typedef _Float16 f16x2 __attribute__((ext_vector_type(2)));

#define NB 256   // batch
#define NT 512   // time
#define NI 64    // input
#define NH 256   // hidden
#define SPB 2    // sequences per block
#define NBLK (NB / SPB)   // 128 blocks
#define THR 1024

// whh packed: f16x2 flat n = ((g*8 + i)*1024 + tid)*4 + e
//   lane tid=(j*4+qt): K = qt*64 + i*8 + 2e + {0,1}, row = g*256 + j
#define WHH_N (3*8*1024*4)   // 98304 f16x2 = 384 KB
// wih packed: f16x2 flat m = ((g*2 + i2)*1024 + tid)*4 + e
//   lane tid=(j*4+qt): K = qt*16 + i2*8 + 2e + {0,1}, row = g*256 + j
#define WIH_N (3*2*1024*4)   // 24576 f16x2 = 96 KB

// ---------------- weight prep: fp32 -> f16x2, lane-major layouts ----------------
__global__ __launch_bounds__(256) void gru_prep_kernel(
    const float* __restrict__ w_ih, const float* __restrict__ w_hh,
    f16x2* __restrict__ whh_p, f16x2* __restrict__ wih_p)
{
  int n = blockIdx.x * 256 + threadIdx.x;
  if (n < WHH_N) {
    int e = n & 3, t = (n >> 2) & 1023, i = (n >> 12) & 7, g = n >> 15;
    int j = t >> 2, qt = t & 3;
    int K = qt * 64 + i * 8 + 2 * e;
    const float* src = w_hh + (g * 256 + j) * 256 + K;
    whh_p[n] = f16x2{(_Float16)src[0], (_Float16)src[1]};
  } else if (n < WHH_N + WIH_N) {
    int m = n - WHH_N;
    int e = m & 3, t = (m >> 2) & 1023, i2 = (m >> 12) & 1, g = m >> 13;
    int j = t >> 2, qt = t & 3;
    int K = qt * 16 + i2 * 8 + 2 * e;
    const float* src = w_ih + (g * 256 + j) * 64 + K;
    wih_p[m] = f16x2{(_Float16)src[0], (_Float16)src[1]};
  }
}

__device__ __forceinline__ float sigm(float v) {
  return __builtin_amdgcn_rcpf(1.0f + __expf(-v));
}
__device__ __forceinline__ float tanh_f(float v) {
  return 1.0f - 2.0f * __builtin_amdgcn_rcpf(1.0f + __expf(2.0f * v));
}

#define FDOT(W, X, A) __builtin_amdgcn_fdot2(__builtin_bit_cast(f16x2, W), \
                                             __builtin_bit_cast(f16x2, X), A, false)
#define GR(s, k) gr##s##k
#define GZ(s, k) gz##s##k
#define GN(s, k) gn##s##k

// ---------------- persistent recurrent kernel: 1 block = 2 sequences ----------------
// 1024 threads, lane = (j = tid>>2, qt = tid&3): qt is IN-WAVE, so the 4-way K-split
// combines via 2 x __shfl_xor (no LDS partials, ONE barrier per step).
// All weights streamed from L2 (no register residency — R3-5 miscompiled; no big LDS).
__global__ __launch_bounds__(THR, 4) void gru_kernel(
    const float* __restrict__ x,      // [B, T, I]
    const float* __restrict__ b_ih,   // [768]
    const float* __restrict__ b_hh,   // [768]
    const float* __restrict__ w_out,  // [256]
    const float* __restrict__ b_out,  // [1]
    const f16x2* __restrict__ whh_p,
    const f16x2* __restrict__ wih_p,
    float* __restrict__ out)          // [T, B]
{
  __shared__ __align__(16) _Float16 x_lds[SPB][4][64];    // 1 KB
  __shared__ __align__(16) _Float16 h_lds[2][SPB][4][72]; // 2.25 KB (72 = 64 + 8 pad -> distinct banks per qt)
  __shared__ float red[2][SPB][16];

  const int tid = threadIdx.x;
  const int j   = tid >> 2;
  const int qt  = tid & 3;
  const int b0  = blockIdx.x * SPB;

  const float bih0 = b_ih[j], bih1 = b_ih[256 + j], bih2 = b_ih[512 + j];
  const float bhh0 = b_hh[j], bhh1 = b_hh[256 + j], bhh2 = b_hh[512 + j];
  const float wo = w_out[j];
  const float bo = b_out[0];

  float h_s0 = 0.0f, h_s1 = 0.0f;
  if (tid < SPB * 4 * 72) ((_Float16*)h_lds[0])[tid] = (_Float16)0.0f;

  const float* xb0 = x + (size_t)(b0 + 0) * (NT * NI);
  const float* xb1 = x + (size_t)(b0 + 1) * (NT * NI);
  const float4* whh4 = (const float4*)whh_p;
  const float4* wih4 = (const float4*)wih_p;
  __syncthreads();

  for (int tc = 0; tc < NT / 4; ++tc) {
    // ---- stage x (f16) for 4 timesteps x 2 seqs ----
    if (tid < 512) {
      int s = tid >> 8, i = tid & 255;
      const float* src = s ? xb1 : xb0;
      x_lds[s][i >> 6][i & 63] = (_Float16)src[tc * 256 + i];
    }
    __syncthreads();

    // ---- gi qt-partials for 4 steps x 2 seqs (named scalars; combined later by shfl) ----
    float gr00, gr01, gr02, gr03, gr10, gr11, gr12, gr13;
    float gz00, gz01, gz02, gz03, gz10, gz11, gz12, gz13;
    float gn00, gn01, gn02, gn03, gn10, gn11, gn12, gn13;
#define GI_ONE(s, k, ACC) { \
    const _Float16* xp = &x_lds[s][k][qt * 16]; \
    float4 X0 = *(const float4*)xp; \
    float4 X1 = *(const float4*)(xp + 8); \
    float a = 0.0f; \
    a = FDOT(W0.x, X0.x, a); a = FDOT(W0.y, X0.y, a); \
    a = FDOT(W0.z, X0.z, a); a = FDOT(W0.w, X0.w, a); \
    a = FDOT(W1.x, X1.x, a); a = FDOT(W1.y, X1.y, a); \
    a = FDOT(W1.z, X1.z, a); a = FDOT(W1.w, X1.w, a); \
    ACC = a; }
#define GI_GATE(g, A00, A01, A02, A03, A10, A11, A12, A13) { \
    float4 W0 = wih4[((g) * 2 + 0) * 1024 + tid]; \
    float4 W1 = wih4[((g) * 2 + 1) * 1024 + tid]; \
    GI_ONE(0, 0, A00) GI_ONE(0, 1, A01) GI_ONE(0, 2, A02) GI_ONE(0, 3, A03) \
    GI_ONE(1, 0, A10) GI_ONE(1, 1, A11) GI_ONE(1, 2, A12) GI_ONE(1, 3, A13) }
    GI_GATE(0, gr00, gr01, gr02, gr03, gr10, gr11, gr12, gr13)
    GI_GATE(1, gz00, gz01, gz02, gz03, gz10, gz11, gz12, gz13)
    GI_GATE(2, gn00, gn01, gn02, gn03, gn10, gn11, gn12, gn13)
#undef GI_GATE
#undef GI_ONE

    // ---- 4 recurrent steps ----
#define STEP(k) { \
    const int t = tc * 4 + (k); \
    const float4* h0q = (const float4*)&h_lds[(k) & 1][0][qt][0]; \
    const float4* h1q = (const float4*)&h_lds[(k) & 1][1][qt][0]; \
    float R0 = 0, Z0 = 0, N0 = 0, R1 = 0, Z1 = 0, N1 = 0; \
    _Pragma("unroll") \
    for (int i = 0; i < 8; ++i) { \
      float4 Wr = whh4[(0 * 8 + i) * 1024 + tid]; \
      float4 Wz = whh4[(1 * 8 + i) * 1024 + tid]; \
      float4 Wn = whh4[(2 * 8 + i) * 1024 + tid]; \
      float4 H0 = h0q[i]; \
      float4 H1 = h1q[i]; \
      R0 = FDOT(Wr.x, H0.x, R0); R0 = FDOT(Wr.y, H0.y, R0); \
      R0 = FDOT(Wr.z, H0.z, R0); R0 = FDOT(Wr.w, H0.w, R0); \
      Z0 = FDOT(Wz.x, H0.x, Z0); Z0 = FDOT(Wz.y, H0.y, Z0); \
      Z0 = FDOT(Wz.z, H0.z, Z0); Z0 = FDOT(Wz.w, H0.w, Z0); \
      N0 = FDOT(Wn.x, H0.x, N0); N0 = FDOT(Wn.y, H0.y, N0); \
      N0 = FDOT(Wn.z, H0.z, N0); N0 = FDOT(Wn.w, H0.w, N0); \
      R1 = FDOT(Wr.x, H1.x, R1); R1 = FDOT(Wr.y, H1.y, R1); \
      R1 = FDOT(Wr.z, H1.z, R1); R1 = FDOT(Wr.w, H1.w, R1); \
      Z1 = FDOT(Wz.x, H1.x, Z1); Z1 = FDOT(Wz.y, H1.y, Z1); \
      Z1 = FDOT(Wz.z, H1.z, Z1); Z1 = FDOT(Wz.w, H1.w, Z1); \
      N1 = FDOT(Wn.x, H1.x, N1); N1 = FDOT(Wn.y, H1.y, N1); \
      N1 = FDOT(Wn.z, H1.z, N1); N1 = FDOT(Wn.w, H1.w, N1); \
    } \
    float sr0 = R0 + GR(0, k); sr0 += __shfl_xor(sr0, 1); sr0 += __shfl_xor(sr0, 2); \
    float sz0 = Z0 + GZ(0, k); sz0 += __shfl_xor(sz0, 1); sz0 += __shfl_xor(sz0, 2); \
    float sn0 = N0;            sn0 += __shfl_xor(sn0, 1); sn0 += __shfl_xor(sn0, 2); \
    float si0 = GN(0, k);      si0 += __shfl_xor(si0, 1); si0 += __shfl_xor(si0, 2); \
    float sr1 = R1 + GR(1, k); sr1 += __shfl_xor(sr1, 1); sr1 += __shfl_xor(sr1, 2); \
    float sz1 = Z1 + GZ(1, k); sz1 += __shfl_xor(sz1, 1); sz1 += __shfl_xor(sz1, 2); \
    float sn1 = N1;            sn1 += __shfl_xor(sn1, 1); sn1 += __shfl_xor(sn1, 2); \
    float si1 = GN(1, k);      si1 += __shfl_xor(si1, 1); si1 += __shfl_xor(si1, 2); \
    float rr0 = sigm(bih0 + bhh0 + sr0); \
    float zz0 = sigm(bih1 + bhh1 + sz0); \
    float nn0 = tanh_f(bih2 + si0 + rr0 * (bhh2 + sn0)); \
    h_s0 = (1.0f - zz0) * nn0 + zz0 * h_s0; \
    float rr1 = sigm(bih0 + bhh0 + sr1); \
    float zz1 = sigm(bih1 + bhh1 + sz1); \
    float nn1 = tanh_f(bih2 + si1 + rr1 * (bhh2 + sn1)); \
    h_s1 = (1.0f - zz1) * nn1 + zz1 * h_s1; \
    if (qt == 0) h_lds[((k) + 1) & 1][0][j >> 6][j & 63] = (_Float16)h_s0; \
    if (qt == 1) h_lds[((k) + 1) & 1][1][j >> 6][j & 63] = (_Float16)h_s1; \
    float po = (qt == 0) ? h_s0 * wo : ((qt == 1) ? h_s1 * wo : 0.0f); \
    po += __shfl_xor(po, 4); po += __shfl_xor(po, 8); \
    po += __shfl_xor(po, 16); po += __shfl_xor(po, 32); \
    if ((tid & 63) < 2) red[(k) & 1][tid & 3][tid >> 6] = po; \
    __syncthreads(); \
    if (tid < 32) { \
      int ss = tid >> 4, w = tid & 15; \
      float v = red[(k) & 1][ss][w]; \
      v += __shfl_xor(v, 1); v += __shfl_xor(v, 2); \
      v += __shfl_xor(v, 4); v += __shfl_xor(v, 8); \
      if (w == 0) out[t * NB + b0 + ss] = v + bo; \
    } }

    STEP(0) STEP(1) STEP(2) STEP(3)
#undef STEP
  }
}

extern "C" void kernel_launch(void* const* d_in, const int* in_sizes, int n_in,
                              void* d_out, int out_size, void* d_ws, size_t ws_size,
                              hipStream_t stream) {
  const float* x     = (const float*)d_in[0];
  const float* w_ih  = (const float*)d_in[1];
  const float* w_hh  = (const float*)d_in[2];
  const float* b_ih  = (const float*)d_in[3];
  const float* b_hh  = (const float*)d_in[4];
  const float* w_out = (const float*)d_in[5];
  const float* b_out = (const float*)d_in[6];
  float* out = (float*)d_out;

  f16x2* whh_p = (f16x2*)d_ws;       // 384 KB
  f16x2* wih_p = whh_p + WHH_N;      // 96 KB   (total 480 KB)

  gru_prep_kernel<<<480, 256, 0, stream>>>(w_ih, w_hh, whh_p, wih_p);
  gru_kernel<<<NBLK, THR, 0, stream>>>(x, b_ih, b_hh, w_out, b_out,
                                       whh_p, wih_p, out);
}

// Round 9
// 3740.030 us; speedup vs baseline: 1.3877x; 1.3877x over previous
//
#include <hip/hip_runtime.h>

typedef _Float16 half8 __attribute__((ext_vector_type(8)));
typedef float floatx4 __attribute__((ext_vector_type(4)));

#define NB 256    // batch
#define NT 512    // time
#define NI 64     // input
#define NH 256    // hidden
#define NSEQ 16   // sequences per block
#define NBLK (NB / NSEQ)   // 16 blocks
#define THR 1024           // 16 waves

// B-fragment pack: 480 (tile,kb) blocks x 64 lanes x 8 f16 = 245760 f16 = 480 KB.
// Column space (N=1024): [0,256)=r, [256,512)=z, [512,768)=h_n, [768,1024)=i_n.
// K space (320): [0,256)=h (w_hh), [256,320)=x (w_ih).
// tile tt (16 cols each): tt<16: r (kb 0..9); 16..31: z (kb 0..9); 32..47: h_n (kb 0..7);
// 48..63: i_n (kb 8..9). Flat frag index f: r: tt*10+kb; z: 160+..; h_n: 320+(tt-32)*8+kb;
// i_n: 448+(tt-48)*2+(kb-8).
// Element: wb[f*512 + lane*8 + i] = W[k = kb*32 + (lane>>4)*8 + i][n = tt*16 + (lane&15)]
#define WB_N (480 * 512)

__global__ __launch_bounds__(256) void gru_prep_kernel(
    const float* __restrict__ w_ih, const float* __restrict__ w_hh,
    _Float16* __restrict__ wb)
{
  int n = blockIdx.x * 256 + threadIdx.x;
  if (n >= WB_N) return;
  int i = n & 7, l = (n >> 3) & 63, f = n >> 9;
  int q = l >> 4, col = l & 15;
  int tt, kb, gate;
  if (f < 160)      { tt = f / 10;               kb = f % 10;        gate = 0; }
  else if (f < 320) { int f2 = f - 160; tt = f2 / 10; kb = f2 % 10;  gate = 1; }
  else if (f < 448) { int f3 = f - 320; tt = f3 / 8;  kb = f3 % 8;   gate = 2; }
  else              { int f4 = f - 448; tt = f4 / 2;  kb = 8 + (f4 & 1); gate = 3; }
  int j = (tt & 15) * 16 + col;     // hidden unit 0..255 within the gate
  int k = kb * 32 + q * 8 + i;      // K index 0..319
  float v;
  if (gate == 0)      v = (k < 256) ? w_hh[(0   + j) * 256 + k] : w_ih[(0   + j) * 64 + (k - 256)];
  else if (gate == 1) v = (k < 256) ? w_hh[(256 + j) * 256 + k] : w_ih[(256 + j) * 64 + (k - 256)];
  else if (gate == 2) v = w_hh[(512 + j) * 256 + k];              // h_n: k < 256 by construction
  else                v = w_ih[(512 + j) * 64 + (k - 256)];       // i_n: k >= 256 by construction
  wb[n] = (_Float16)v;
}

__device__ __forceinline__ float sigm(float v) {
  return __builtin_amdgcn_rcpf(1.0f + __expf(-v));
}
__device__ __forceinline__ float tanh_f(float v) {
  return 1.0f - 2.0f * __builtin_amdgcn_rcpf(1.0f + __expf(2.0f * v));
}

// ---------------- batched MFMA recurrence: 1 block = 16 sequences, 16 CUs total ----------------
// Per step: G[16 x 1024] = Hext[16 x 320] @ B, via mfma_f32_16x16x32_f16.
// Wave w computes tiles {w (r), 16+w (z), 32+w (h_n), 48+w (i_n)} = 30 MFMAs, balanced.
// Layouts (HW-verified, m89/m120): A[m=lane&15][k=(lane>>4)*8+i]; B[n=lane&15][k=...];
// D[col=lane&15][row=(lane>>4)*4+reg] with col=n(gate), row=m(seq).
__global__ __launch_bounds__(THR) void gru_kernel(
    const float* __restrict__ x,      // [B, T, I]
    const float* __restrict__ b_ih,   // [768]
    const float* __restrict__ b_hh,   // [768]
    const float* __restrict__ w_out,  // [256]
    const float* __restrict__ b_out,  // [1]
    const _Float16* __restrict__ wb,  // packed B fragments
    float* __restrict__ out)          // [T, B]
{
  __shared__ __align__(16) _Float16 H[NSEQ][328];   // [seq][320 K + 8 pad]  10.25 KB
  __shared__ __align__(16) float    G[1024][20];    // [col][16 seq + 4 pad] 80 KB
  __shared__ float red[NSEQ][4];

  const int tid  = threadIdx.x;
  const int lane = tid & 63;
  const int w    = tid >> 6;        // wave 0..15
  const int q    = lane >> 4;       // quad 0..3
  const int col  = lane & 15;
  const int b0   = blockIdx.x * NSEQ;

  // epilogue identity: thread -> (hidden unit j, seq-block sb of 4 seqs)
  const int j  = tid & 255;
  const int sb = tid >> 8;          // 0..3

  const float bihr = b_ih[j], bihz = b_ih[256 + j], bihn = b_ih[512 + j];
  const float bhhr = b_hh[j], bhhz = b_hh[256 + j], bhhn = b_hh[512 + j];
  const float wo = w_out[j];
  const float bo = b_out[0];

  // ---- init: h-part of H = 0; x-part = x[., t=0, .] ----
  for (int idx = tid; idx < NSEQ * 256; idx += THR) H[idx >> 8][idx & 255] = (_Float16)0.0f;
  {
    int s = tid >> 6, ii = tid & 63;
    H[s][256 + ii] = (_Float16)x[(size_t)(b0 + s) * (NT * NI) + ii];
  }
  float h0 = 0.0f, h1 = 0.0f, h2 = 0.0f, h3 = 0.0f;

  // per-wave B-fragment base pointers (lane-resolved)
  const _Float16* pR = wb + (size_t)(       w * 10) * 512 + lane * 8;
  const _Float16* pZ = wb + (size_t)(160 +  w * 10) * 512 + lane * 8;
  const _Float16* pN = wb + (size_t)(320 +  w * 8 ) * 512 + lane * 8;
  const _Float16* pI = wb + (size_t)(448 +  w * 2 ) * 512 + lane * 8;

  __syncthreads();

  for (int t = 0; t < NT; ++t) {
    // ---- prefetch x for step t+1 (one float per thread, coalesced per seq) ----
    float xv = 0.0f;
    if (t + 1 < NT) xv = x[(size_t)(b0 + (tid >> 6)) * (NT * NI) + (t + 1) * 64 + (tid & 63)];

    // ---- GEMM: 4 tiles per wave, K = 320 (r,z) / 256 (h_n) / 64 (i_n) ----
    floatx4 cR = {0, 0, 0, 0}, cZ = {0, 0, 0, 0}, cN = {0, 0, 0, 0}, cI = {0, 0, 0, 0};
    #pragma unroll
    for (int kb = 0; kb < 10; ++kb) {
      half8 a = *(const half8*)&H[col][kb * 32 + q * 8];   // A-frag (shared by all 4 tiles)
      half8 bR = *(const half8*)(pR + (size_t)kb * 512);
      half8 bZ = *(const half8*)(pZ + (size_t)kb * 512);
      cR = __builtin_amdgcn_mfma_f32_16x16x32_f16(a, bR, cR, 0, 0, 0);
      cZ = __builtin_amdgcn_mfma_f32_16x16x32_f16(a, bZ, cZ, 0, 0, 0);
      if (kb < 8) {
        half8 bN = *(const half8*)(pN + (size_t)kb * 512);
        cN = __builtin_amdgcn_mfma_f32_16x16x32_f16(a, bN, cN, 0, 0, 0);
      } else {
        half8 bI = *(const half8*)(pI + (size_t)(kb - 8) * 512);
        cI = __builtin_amdgcn_mfma_f32_16x16x32_f16(a, bI, cI, 0, 0, 0);
      }
    }
    // D -> G: lane holds col (w*16+col), seqs q*4..q*4+3 (contiguous -> one b128)
    *(floatx4*)&G[      w * 16 + col][q * 4] = cR;
    *(floatx4*)&G[256 + w * 16 + col][q * 4] = cZ;
    *(floatx4*)&G[512 + w * 16 + col][q * 4] = cN;
    *(floatx4*)&G[768 + w * 16 + col][q * 4] = cI;
    __syncthreads();   // B1: G complete; H reads of step t done

    // ---- epilogue: thread (j, sb) handles unit j for seqs sb*4..sb*4+3 ----
    floatx4 Gr = *(const floatx4*)&G[j][sb * 4];
    floatx4 Gz = *(const floatx4*)&G[256 + j][sb * 4];
    floatx4 Gn = *(const floatx4*)&G[512 + j][sb * 4];
    floatx4 Gi = *(const floatx4*)&G[768 + j][sb * 4];
#define GATE(m, hvar) { \
    float rr = sigm(Gr[m] + bihr + bhhr); \
    float zz = sigm(Gz[m] + bihz + bhhz); \
    float nn = tanh_f(Gi[m] + bihn + rr * (Gn[m] + bhhn)); \
    hvar = (1.0f - zz) * nn + zz * hvar; \
    H[sb * 4 + (m)][j] = (_Float16)hvar; }
    GATE(0, h0) GATE(1, h1) GATE(2, h2) GATE(3, h3)
#undef GATE
    // store prefetched x for step t+1
    if (t + 1 < NT) H[tid >> 6][256 + (tid & 63)] = (_Float16)xv;

    // out projection partials: reduce h*wo over the 64 j's in this wave
    float p0 = h0 * wo, p1 = h1 * wo, p2 = h2 * wo, p3 = h3 * wo;
    p0 += __shfl_down(p0, 32); p1 += __shfl_down(p1, 32);
    p2 += __shfl_down(p2, 32); p3 += __shfl_down(p3, 32);
    p0 += __shfl_down(p0, 16); p1 += __shfl_down(p1, 16);
    p2 += __shfl_down(p2, 16); p3 += __shfl_down(p3, 16);
    p0 += __shfl_down(p0, 8);  p1 += __shfl_down(p1, 8);
    p2 += __shfl_down(p2, 8);  p3 += __shfl_down(p3, 8);
    p0 += __shfl_down(p0, 4);  p1 += __shfl_down(p1, 4);
    p2 += __shfl_down(p2, 4);  p3 += __shfl_down(p3, 4);
    p0 += __shfl_down(p0, 2);  p1 += __shfl_down(p1, 2);
    p2 += __shfl_down(p2, 2);  p3 += __shfl_down(p3, 2);
    p0 += __shfl_down(p0, 1);  p1 += __shfl_down(p1, 1);
    p2 += __shfl_down(p2, 1);  p3 += __shfl_down(p3, 1);
    if (lane == 0) {
      int wv = w & 3;              // wave-within-sb (4 waves share an sb)
      red[sb * 4 + 0][wv] = p0;
      red[sb * 4 + 1][wv] = p1;
      red[sb * 4 + 2][wv] = p2;
      red[sb * 4 + 3][wv] = p3;
    }
    __syncthreads();   // B2: H(t+1), red complete

    // finalize out (wave 0 only; safe vs next red writes: they're after B1(t+1))
    if (tid < 64) {
      int s = tid >> 2, part = tid & 3;
      float v = red[s][part];
      v += __shfl_xor(v, 1);
      v += __shfl_xor(v, 2);
      if (part == 0) out[t * NB + b0 + s] = v + bo;
    }
  }
}

extern "C" void kernel_launch(void* const* d_in, const int* in_sizes, int n_in,
                              void* d_out, int out_size, void* d_ws, size_t ws_size,
                              hipStream_t stream) {
  const float* x     = (const float*)d_in[0];
  const float* w_ih  = (const float*)d_in[1];
  const float* w_hh  = (const float*)d_in[2];
  const float* b_ih  = (const float*)d_in[3];
  const float* b_hh  = (const float*)d_in[4];
  const float* w_out = (const float*)d_in[5];
  const float* b_out = (const float*)d_in[6];
  float* out = (float*)d_out;

  _Float16* wb = (_Float16*)d_ws;   // 480 KB packed B fragments

  gru_prep_kernel<<<(WB_N + 255) / 256, 256, 0, stream>>>(w_ih, w_hh, wb);
  gru_kernel<<<NBLK, THR, 0, stream>>>(x, b_ih, b_hh, w_out, b_out, wb, out);
}

// Round 10
// 1329.248 us; speedup vs baseline: 3.9045x; 2.8136x over previous
//
#include <hip/hip_runtime.h>

typedef _Float16 half8 __attribute__((ext_vector_type(8)));
typedef float floatx4 __attribute__((ext_vector_type(4)));

#define NB 256    // batch
#define NT 512    // time
#define NI 64     // input
#define NH 256    // hidden
#define NSEQ 16   // sequences per block
#define NBLK (NB / NSEQ)   // 16 blocks
#define THR 1024           // 16 waves
#define HS 344             // H row stride in f16 (172 words == 12 mod 32: conflict-light)

// B-fragment pack (VALIDATED in R9, absmax 0.00195): 480 frags x 64 lanes x 8 f16.
// Cols: [0,256)=r, [256,512)=z, [512,768)=h_n, [768,1024)=i_n. K: [0,256)=h, [256,320)=x.
// frag f: r: tt*10+kb; z: 160+tt*10+kb; h_n: 320+tt*8+kb (kb<8); i_n: 448+tt*2+(kb-8).
// wb[f*512 + lane*8 + i] = W[k = kb*32 + (lane>>4)*8 + i][n = tt*16 + (lane&15)]
#define WB_N (480 * 512)

__global__ __launch_bounds__(256) void gru_prep_kernel(
    const float* __restrict__ w_ih, const float* __restrict__ w_hh,
    _Float16* __restrict__ wb)
{
  int n = blockIdx.x * 256 + threadIdx.x;
  if (n >= WB_N) return;
  int i = n & 7, l = (n >> 3) & 63, f = n >> 9;
  int q = l >> 4, col = l & 15;
  int tt, kb, gate;
  if (f < 160)      { tt = f / 10;               kb = f % 10;        gate = 0; }
  else if (f < 320) { int f2 = f - 160; tt = f2 / 10; kb = f2 % 10;  gate = 1; }
  else if (f < 448) { int f3 = f - 320; tt = f3 / 8;  kb = f3 % 8;   gate = 2; }
  else              { int f4 = f - 448; tt = f4 / 2;  kb = 8 + (f4 & 1); gate = 3; }
  int j = (tt & 15) * 16 + col;
  int k = kb * 32 + q * 8 + i;
  float v;
  if (gate == 0)      v = (k < 256) ? w_hh[(0   + j) * 256 + k] : w_ih[(0   + j) * 64 + (k - 256)];
  else if (gate == 1) v = (k < 256) ? w_hh[(256 + j) * 256 + k] : w_ih[(256 + j) * 64 + (k - 256)];
  else if (gate == 2) v = w_hh[(512 + j) * 256 + k];
  else                v = w_ih[(512 + j) * 64 + (k - 256)];
  wb[n] = (_Float16)v;
}

__device__ __forceinline__ float sigm(float v) {
  return __builtin_amdgcn_rcpf(1.0f + __expf(-v));
}
__device__ __forceinline__ float tanh_f(float v) {
  return 1.0f - 2.0f * __builtin_amdgcn_rcpf(1.0f + __expf(2.0f * v));
}

#define MFMA16(a, b, c) __builtin_amdgcn_mfma_f32_16x16x32_f16(a, b, c, 0, 0, 0)

// ---------------- batched MFMA recurrence: 1 block = 16 sequences ----------------
// Wave w owns cols w*16..w*16+15 of all 4 gates. Weights: r(10)+z(0..5) frags in
// REGISTERS (64 VGPR), n(0..7) in LDS (128 KB), z(6..9)+i(2) streamed from L1/L2.
// Epilogue fully in-register (D frag holds (col=unit, row=seq)); h state in 4 scalars;
// ONE barrier per step; H double-buffered at stride 344.
__global__ __launch_bounds__(THR) void gru_kernel(
    const float* __restrict__ x,      // [B, T, I]
    const float* __restrict__ b_ih,   // [768]
    const float* __restrict__ b_hh,   // [768]
    const float* __restrict__ w_out,  // [256]
    const float* __restrict__ b_out,  // [1]
    const _Float16* __restrict__ wb,  // packed B fragments
    float* __restrict__ out)          // [T, B]
{
  __shared__ __align__(16) _Float16 H[2][NSEQ][HS];   // 22 KB, double-buffered
  __shared__ __align__(16) _Float16 WN[8 * 16 * 512]; // 128 KB: n-gate frags
  __shared__ float red[2][NSEQ][16];                  // 2 KB

  const int tid  = threadIdx.x;
  const int lane = tid & 63;
  const int w    = tid >> 6;        // wave 0..15
  const int q    = lane >> 4;       // quad 0..3
  const int col  = lane & 15;
  const int b0   = blockIdx.x * NSEQ;
  const int j    = w * 16 + col;    // hidden unit owned in epilogue

  // ---- stage n-gate frags to LDS (128 KB, coalesced float4) ----
  {
    const float4* src = (const float4*)(wb + 320 * 512);
    float4* dst = (float4*)WN;
    #pragma unroll
    for (int it = 0; it < 8; ++it) dst[tid + it * THR] = src[tid + it * THR];
  }

  // ---- persistent B fragments: 16 named half8 (64 VGPRs) ----
  const _Float16* wbL = wb + (size_t)lane * 8;
#define LBR(k) const half8 BR##k = *(const half8*)(wbL + (size_t)(w * 10 + (k)) * 512);
  LBR(0) LBR(1) LBR(2) LBR(3) LBR(4) LBR(5) LBR(6) LBR(7) LBR(8) LBR(9)
#undef LBR
#define LBZ(k) const half8 BZ##k = *(const half8*)(wbL + (size_t)(160 + w * 10 + (k)) * 512);
  LBZ(0) LBZ(1) LBZ(2) LBZ(3) LBZ(4) LBZ(5)
#undef LBZ
  // streamed fragment pointers (loop-invariant -> L1/L2 hot)
  const half8* sZ6 = (const half8*)(wbL + (size_t)(160 + w * 10 + 6) * 512);
  const half8* sZ7 = (const half8*)(wbL + (size_t)(160 + w * 10 + 7) * 512);
  const half8* sZ8 = (const half8*)(wbL + (size_t)(160 + w * 10 + 8) * 512);
  const half8* sZ9 = (const half8*)(wbL + (size_t)(160 + w * 10 + 9) * 512);
  const half8* sI0 = (const half8*)(wbL + (size_t)(448 + w * 2 + 0) * 512);
  const half8* sI1 = (const half8*)(wbL + (size_t)(448 + w * 2 + 1) * 512);

  const float br   = b_ih[j] + b_hh[j];
  const float bz   = b_ih[256 + j] + b_hh[256 + j];
  const float bin_ = b_ih[512 + j];
  const float bhn  = b_hh[512 + j];
  const float wo   = w_out[j];
  const float bo   = b_out[0];

  // ---- init: zero H (both buffers), then x(t=0) into H[0] ----
  {
    float4* hz = (float4*)H;
    #pragma unroll
    for (int it = 0; it < 2; ++it) {
      int idx = tid + it * THR;
      if (idx < (int)(sizeof(H) / 16)) hz[idx] = float4{0, 0, 0, 0};
    }
  }
  __syncthreads();
  H[0][tid >> 6][256 + (tid & 63)] =
      (_Float16)x[(size_t)(b0 + (tid >> 6)) * (NT * NI) + (tid & 63)];
  float h0 = 0.0f, h1 = 0.0f, h2 = 0.0f, h3 = 0.0f;
  __syncthreads();

  for (int t = 0; t < NT; ++t) {
    const int cur = t & 1, nxt = cur ^ 1;
    // streamed frags + x prefetch: issue all global loads up front
    half8 SZ6 = *sZ6, SZ7 = *sZ7, SZ8 = *sZ8, SZ9 = *sZ9, SI0i = *sI0, SI1i = *sI1;
    float xv = 0.0f;
    if (t + 1 < NT)
      xv = x[(size_t)(b0 + (tid >> 6)) * (NT * NI) + (t + 1) * 64 + (tid & 63)];

    // ---- GEMM: A row = seq = col (validated R9), 30 MFMAs/wave ----
    const _Float16* hrow = &H[cur][col][q * 8];
    floatx4 cR = {0, 0, 0, 0}, cZ = {0, 0, 0, 0}, cN = {0, 0, 0, 0}, cI = {0, 0, 0, 0};
#define KBN(k, BZk) { \
    half8 a = *(const half8*)(hrow + (k) * 32); \
    cR = MFMA16(a, BR##k, cR); \
    cZ = MFMA16(a, BZk, cZ); \
    cN = MFMA16(a, *(const half8*)&WN[(w * 8 + (k)) * 512 + lane * 8], cN); }
    KBN(0, BZ0) KBN(1, BZ1) KBN(2, BZ2) KBN(3, BZ3) KBN(4, BZ4) KBN(5, BZ5)
    KBN(6, SZ6) KBN(7, SZ7)
#undef KBN
    { half8 a = *(const half8*)(hrow + 8 * 32);
      cR = MFMA16(a, BR8, cR); cZ = MFMA16(a, SZ8, cZ); cI = MFMA16(a, SI0i, cI); }
    { half8 a = *(const half8*)(hrow + 9 * 32);
      cR = MFMA16(a, BR9, cR); cZ = MFMA16(a, SZ9, cZ); cI = MFMA16(a, SI1i, cI); }

    // ---- in-register epilogue: lane owns (j, seqs q*4..q*4+3) ----
#define GATE(m, hvar) { \
    float rr = sigm(cR[m] + br); \
    float zz = sigm(cZ[m] + bz); \
    float nn = tanh_f(cI[m] + bin_ + rr * (cN[m] + bhn)); \
    hvar = (1.0f - zz) * nn + zz * hvar; \
    H[nxt][q * 4 + (m)][j] = (_Float16)hvar; }
    GATE(0, h0) GATE(1, h1) GATE(2, h2) GATE(3, h3)
#undef GATE
    if (t + 1 < NT) H[nxt][tid >> 6][256 + (tid & 63)] = (_Float16)xv;

    // out-projection: reduce h*wo over 16 cols in-wave, partials to red
    float p0 = h0 * wo, p1 = h1 * wo, p2 = h2 * wo, p3 = h3 * wo;
    p0 += __shfl_xor(p0, 1); p1 += __shfl_xor(p1, 1);
    p2 += __shfl_xor(p2, 1); p3 += __shfl_xor(p3, 1);
    p0 += __shfl_xor(p0, 2); p1 += __shfl_xor(p1, 2);
    p2 += __shfl_xor(p2, 2); p3 += __shfl_xor(p3, 2);
    p0 += __shfl_xor(p0, 4); p1 += __shfl_xor(p1, 4);
    p2 += __shfl_xor(p2, 4); p3 += __shfl_xor(p3, 4);
    p0 += __shfl_xor(p0, 8); p1 += __shfl_xor(p1, 8);
    p2 += __shfl_xor(p2, 8); p3 += __shfl_xor(p3, 8);
    if (col == 0) {
      red[cur][q * 4 + 0][w] = p0;
      red[cur][q * 4 + 1][w] = p1;
      red[cur][q * 4 + 2][w] = p2;
      red[cur][q * 4 + 3][w] = p3;
    }
    __syncthreads();   // the single per-step barrier

    // finalize out for step t (waves 0-3; red double-buffered vs step t+1 writes)
    if (tid < 256) {
      int s = tid >> 4, w2 = tid & 15;
      float v = red[cur][s][w2];
      v += __shfl_xor(v, 1);
      v += __shfl_xor(v, 2);
      v += __shfl_xor(v, 4);
      v += __shfl_xor(v, 8);
      if (w2 == 0) out[t * NB + b0 + s] = v + bo;
    }
  }
}

extern "C" void kernel_launch(void* const* d_in, const int* in_sizes, int n_in,
                              void* d_out, int out_size, void* d_ws, size_t ws_size,
                              hipStream_t stream) {
  const float* x     = (const float*)d_in[0];
  const float* w_ih  = (const float*)d_in[1];
  const float* w_hh  = (const float*)d_in[2];
  const float* b_ih  = (const float*)d_in[3];
  const float* b_hh  = (const float*)d_in[4];
  const float* w_out = (const float*)d_in[5];
  const float* b_out = (const float*)d_in[6];
  float* out = (float*)d_out;

  _Float16* wb = (_Float16*)d_ws;   // 480 KB packed B fragments

  gru_prep_kernel<<<(WB_N + 255) / 256, 256, 0, stream>>>(w_ih, w_hh, wb);
  gru_kernel<<<NBLK, THR, 0, stream>>>(x, b_ih, b_hh, w_out, b_out, wb, out);
}